// Round 8
// baseline (14888.156 us; speedup 1.0000x reference)
//
#include <hip/hip_runtime.h>
#include <stdint.h>

using short8 = __attribute__((ext_vector_type(8))) short;
using f32x4  = __attribute__((ext_vector_type(4))) float;
typedef unsigned long long ull;

#define DEV static __device__ __forceinline__

DEV unsigned short f2bf(float f){
  unsigned u = __builtin_bit_cast(unsigned, f);
  u = (u + 0x7FFFu + ((u >> 16) & 1u)) >> 16;
  return (unsigned short)u;
}
DEV float sigm(float x){
  float e = __builtin_amdgcn_exp2f(-1.4426950408889634f * x);
  return __builtin_amdgcn_rcpf(1.0f + e);
}
DEV float tanh_(float x){
  float e = __builtin_amdgcn_exp2f(2.885390081777927f * x); // exp(2x)
  return 1.0f - 2.0f * __builtin_amdgcn_rcpf(e + 1.0f);
}

// ---------------- aux kernels ----------------

__global__ void k_f32_to_bf16(const float* __restrict__ in, unsigned short* __restrict__ out, int n){
  int stride = gridDim.x * blockDim.x * 4;
  for (int i = (blockIdx.x * blockDim.x + threadIdx.x) * 4; i < n; i += stride){
    float4 v = *(const float4*)(in + i);
    ushort4 o4;
    o4.x = f2bf(v.x); o4.y = f2bf(v.y); o4.z = f2bf(v.z); o4.w = f2bf(v.w);
    *(ushort4*)(out + i) = o4;
  }
}

__global__ void k_add_bf16(const float* __restrict__ a, const float* __restrict__ b,
                           unsigned short* __restrict__ out, int n){
  int stride = gridDim.x * blockDim.x * 4;
  for (int i = (blockIdx.x * blockDim.x + threadIdx.x) * 4; i < n; i += stride){
    float4 va = *(const float4*)(a + i);
    float4 vb = *(const float4*)(b + i);
    ushort4 o4;
    o4.x = f2bf(va.x + vb.x); o4.y = f2bf(va.y + vb.y);
    o4.z = f2bf(va.z + vb.z); o4.w = f2bf(va.w + vb.w);
    *(ushort4*)(out + i) = o4;
  }
}

__global__ void k_add_f32(float* __restrict__ o, const float* __restrict__ b, int n){
  int stride = gridDim.x * blockDim.x * 4;
  for (int i = (blockIdx.x * blockDim.x + threadIdx.x) * 4; i < n; i += stride){
    float4 vo = *(const float4*)(o + i);
    float4 vb = *(const float4*)(b + i);
    vo.x += vb.x; vo.y += vb.y; vo.z += vb.z; vo.w += vb.w;
    *(float4*)(o + i) = vo;
  }
}

// Pack [k; r] (f32, [K,4U] each, K split KX|U) into per-(dir,wg,wave,ktile,ntile)
// MFMA B-fragment order (BLOCKED K split: wave w owns ktiles 6w..6w+5)
__global__ void k_pack(const float* __restrict__ k0, const float* __restrict__ r0,
                       const float* __restrict__ k1, const float* __restrict__ r1,
                       unsigned short* __restrict__ out, int E, int KX, int U){
  int n = 2 * E;
  int stride = gridDim.x * blockDim.x;
  for (int i = blockIdx.x * blockDim.x + threadIdx.x; i < n; i += stride){
    int d = i / E, r = i % E;
    const float* Km = d ? k1 : k0;
    const float* Rm = d ? r1 : r0;
    int j    = r & 7;  int q = r >> 3;
    int lane = q & 63; q >>= 6;
    int nt   = q & 3;  q >>= 2;
    int kt   = q % 6;  q /= 6;
    int w    = q & 3;  int wg = q >> 2;
    int k    = (w*6 + kt)*32 + ((lane >> 4) << 3) + j;
    int col  = nt * U + wg*16 + (lane & 15);   // gate-major global column
    float v  = (k < KX) ? Km[(size_t)k * (4*U) + col]
                        : Rm[(size_t)(k - KX) * (4*U) + col];
    out[i] = f2bf(v);
  }
}

// ---------------- persistent recurrence kernel (R5 protocol + ablation MODE) ----
// MODE 0: full (real path, identical to round-5 kernel)
// MODE 1: NOPOLL  - wait loop removed, everything else kept
// MODE 2: NOH     - h loads + h MFMAs removed, poll + publish kept
// MODE 3: LOCAL   - no poll, no h, no counter publish (per-WG local floor)
template<int KX, int U, int WGS, int MODE>
__global__ __launch_bounds__(256, 1)
void lstm_rec(const unsigned short* __restrict__ xab,    // [64][512][KX] bf16
              const unsigned short* __restrict__ packedB,
              const float* __restrict__ bias_f,
              const float* __restrict__ bias_b,
              const int*   __restrict__ sizes,
              unsigned short* __restrict__ hbuf,         // [2 dirs][2][64][U] bf16
              unsigned int*  __restrict__ counters,      // [2 dirs][32]
              float* __restrict__ out_f,                 // [64][512][U]
              float* __restrict__ out_b)
{
  constexpr int KTW = 6;               // ktiles per wave (blocked)
  constexpr int T   = 512;

  const int tid  = threadIdx.x;
  const int w    = tid >> 6;
  const int lane = tid & 63;
  const int dir  = (blockIdx.x >= WGS) ? 1 : 0;
  const int wg   = dir ? (int)blockIdx.x - WGS : (int)blockIdx.x;

  const unsigned short* pB = packedB + (size_t)dir * ((size_t)WGS*4*KTW*4*512)
                                     + (size_t)((wg*4 + w)*KTW)*4*512;
  unsigned short* hb  = hbuf + (size_t)dir * (2*64*U);
  unsigned int*   cnt = counters + dir * 32;
  const float* bias = dir ? bias_b : bias_f;
  float* outp       = dir ? out_b : out_f;

  const bool has_h = ((w*KTW + KTW - 1) * 32) >= KX;

  // preload B fragments (step-invariant): 96 VGPRs
  short8 bfr[KTW][4];
  #pragma unroll
  for (int kt = 0; kt < KTW; ++kt)
    #pragma unroll
    for (int nt = 0; nt < 4; ++nt)
      bfr[kt][nt] = *(const short8*)(pB + ((kt*4 + nt)*512) + lane*8);

  // gate-phase ownership: unit u_l (0..15), rows rb..rb+3
  const int u_l = tid & 15;
  const int rb  = (tid >> 4) * 4;
  const int ug  = wg*16 + u_l;
  float bz[4]; int sz[4];
  #pragma unroll
  for (int g = 0; g < 4; ++g) bz[g] = bias[g*U + ug];
  #pragma unroll
  for (int r = 0; r < 4; ++r) sz[r] = sizes[rb + r];
  float c[4]    = {0.f,0.f,0.f,0.f};
  float hreg[4] = {0.f,0.f,0.f,0.f};

  __shared__ float part[4][64][68];

  const int arow  = lane & 15;
  const int kgrp  = (lane >> 4) * 8;
  const int rquad = (lane >> 4) * 4;

  // x fragments, prefetched one step ahead
  short8 xreg[KTW][4];
  {
    const int t0 = dir ? T - 1 : 0;
    #pragma unroll
    for (int kt = 0; kt < KTW; ++kt){
      const int kg = (w*KTW + kt) * 32;
      if (kg < KX){
        #pragma unroll
        for (int mt = 0; mt < 4; ++mt)
          xreg[kt][mt] = *(const short8*)(xab + ((size_t)((mt*16 + arow)*T + t0))*KX + (kg + kgrp));
      }
    }
  }

  for (int s = 0; s < T; ++s){
    const int t   = dir ? (T - 1 - s) : s;
    const int par = s & 1;

    f32x4 acc[4][4];
    #pragma unroll
    for (int mt = 0; mt < 4; ++mt)
      #pragma unroll
      for (int nt = 0; nt < 4; ++nt)
        acc[mt][nt] = (f32x4){0.f, 0.f, 0.f, 0.f};

    // ---- x MFMAs ----
    #pragma unroll
    for (int kt = 0; kt < KTW; ++kt){
      const int kg = (w*KTW + kt) * 32;
      if (kg < KX){
        #pragma unroll
        for (int mt = 0; mt < 4; ++mt)
          #pragma unroll
          for (int nt = 0; nt < 4; ++nt)
            acc[mt][nt] = __builtin_amdgcn_mfma_f32_16x16x32_bf16(xreg[kt][mt], bfr[kt][nt], acc[mt][nt], 0, 0, 0);
      }
    }

    if (s > 0 && has_h){
      // ---- poll (MODE 0/2) ----
      if constexpr (MODE == 0 || MODE == 2){
        const unsigned tgt = (unsigned)WGS * (unsigned)s;
        for (;;){
          unsigned v = __hip_atomic_load(cnt, __ATOMIC_RELAXED, __HIP_MEMORY_SCOPE_AGENT);
          if (v >= tgt) break;
          __builtin_amdgcn_s_sleep(1);
        }
        __builtin_amdgcn_sched_barrier(0);
      }
      // ---- h loads + h MFMAs (MODE 0/1) ----
      if constexpr (MODE == 0 || MODE == 1){
        #pragma unroll
        for (int kt = 0; kt < KTW; ++kt){
          const int kg = (w*KTW + kt) * 32;
          if (kg >= KX){
            #pragma unroll
            for (int mt = 0; mt < 4; ++mt){
              const ull* hp = (const ull*)
                  (hb + (size_t)par*64*U + (size_t)(mt*16 + arow)*U + (kg - KX + kgrp));
              ulonglong2 u;
              u.x = __hip_atomic_load(hp,     __ATOMIC_RELAXED, __HIP_MEMORY_SCOPE_AGENT);
              u.y = __hip_atomic_load(hp + 1, __ATOMIC_RELAXED, __HIP_MEMORY_SCOPE_AGENT);
              short8 a = __builtin_bit_cast(short8, u);
              #pragma unroll
              for (int nt = 0; nt < 4; ++nt)
                acc[mt][nt] = __builtin_amdgcn_mfma_f32_16x16x32_bf16(a, bfr[kt][nt], acc[mt][nt], 0, 0, 0);
            }
          }
        }
      }
    }

    // ---- D-frag scatter: b128 ----
    #pragma unroll
    for (int mt = 0; mt < 4; ++mt)
      #pragma unroll
      for (int nt = 0; nt < 4; ++nt)
        *(f32x4*)&part[w][nt*16 + arow][mt*16 + rquad] = acc[mt][nt];

    __syncthreads();

    // ---- gate phase ----
    f32x4 zg[4];
    #pragma unroll
    for (int g = 0; g < 4; ++g){
      const int cb = g*16 + u_l;
      f32x4 v = *(const f32x4*)&part[0][cb][rb];
      #pragma unroll
      for (int ww = 1; ww < 4; ++ww)
        v += *(const f32x4*)&part[ww][cb][rb];
      zg[g] = v;
    }

    #pragma unroll
    for (int r = 0; r < 4; ++r){
      float ig = sigm (zg[0][r] + bz[0]);
      float fg = sigm (zg[1][r] + bz[1]);
      float gg = tanh_(zg[2][r] + bz[2]);
      float og = sigm (zg[3][r] + bz[3]);
      float cn = fg * c[r] + ig * gg;
      float hn = og * tanh_(cn);
      bool m  = (t < sz[r]);
      c[r] = m ? cn : c[r];
      float h = m ? hn : hreg[r];
      hreg[r] = h;
      __hip_atomic_store(&hb[(size_t)(par ^ 1)*64*U + (size_t)(rb + r)*U + ug],
                         (unsigned short)f2bf(h),
                         __ATOMIC_RELAXED, __HIP_MEMORY_SCOPE_AGENT);
    }

    __syncthreads();   // drains every wave's vmcnt: h stores visible at LLC

    if (s != T - 1){
      if constexpr (MODE != 3){
        if (tid == 0) atomicAdd(cnt, 1u);   // device-scope, fire-and-forget
      }
    }

    // out store AFTER the publish
    #pragma unroll
    for (int r = 0; r < 4; ++r)
      outp[((size_t)(rb + r)*T + t)*U + ug] = hreg[r];

    // x prefetch for next step
    if (s != T - 1){
      const int tn = dir ? t - 1 : t + 1;
      #pragma unroll
      for (int kt = 0; kt < KTW; ++kt){
        const int kg = (w*KTW + kt) * 32;
        if (kg < KX){
          #pragma unroll
          for (int mt = 0; mt < 4; ++mt)
            xreg[kt][mt] = *(const short8*)(xab + ((size_t)((mt*16 + arow)*T + tn))*KX + (kg + kgrp));
        }
      }
    }
  }
}

// ---------------- launch ----------------

extern "C" void kernel_launch(void* const* d_in, const int* in_sizes, int n_in,
                              void* d_out, int out_size, void* d_ws, size_t ws_size,
                              hipStream_t stream){
  const float* x      = (const float*)d_in[0];
  const int*   sizes  = (const int*)  d_in[1];
  const float* enc_kf = (const float*)d_in[2];
  const float* enc_rf = (const float*)d_in[3];
  const float* enc_bf = (const float*)d_in[4];
  const float* enc_kb = (const float*)d_in[5];
  const float* enc_rb = (const float*)d_in[6];
  const float* enc_bb = (const float*)d_in[7];
  const float* dec_kf = (const float*)d_in[8];
  const float* dec_rf = (const float*)d_in[9];
  const float* dec_bf = (const float*)d_in[10];
  const float* dec_kb = (const float*)d_in[11];
  const float* dec_rb = (const float*)d_in[12];
  const float* dec_bb = (const float*)d_in[13];
  float* out = (float*)d_out;
  char*  ws  = (char*)d_ws;

  const size_t o_xbf   = 0;                        // 33,554,432  x bf16
  const size_t o_esum  = o_xbf   + 33554432ull;    // 16,777,216  enc sum bf16
  const size_t o_pBe   = o_esum  + 16777216ull;    //  3,145,728  packed enc (dead after enc -> variant scratch)
  const size_t o_pBd   = o_pBe   + 3145728ull;     //  6,291,456  packed dec
  const size_t o_hfe   = o_pBd   + 6291456ull;     // 33,554,432  enc fwd h f32 (dead after add -> variant out_b lo)
  const size_t o_hbe   = o_hfe   + 33554432ull;    // 33,554,432  enc bwd h f32 (variant out_b hi)
  const size_t o_hbd   = o_hbe   + 33554432ull;    // 67,108,864  dec bwd h f32 (dead after add -> variant out_f)
  const size_t o_hbufe = o_hbd   + 67108864ull;    //    131,072  enc h exchange
  const size_t o_hbufd = o_hbufe + 131072ull;      //    262,144  dec h exchange
  const size_t o_cnte  = o_hbufd + 262144ull;      //      4,096  enc counters
  const size_t o_cntd  = o_cnte  + 4096ull;        //      4,096  dec counters
  const size_t total   = o_cntd  + 4096ull;
  if (ws_size < total) return;

  unsigned short* xbf   = (unsigned short*)(ws + o_xbf);
  unsigned short* esum  = (unsigned short*)(ws + o_esum);
  unsigned short* pBe   = (unsigned short*)(ws + o_pBe);
  unsigned short* pBd   = (unsigned short*)(ws + o_pBd);
  float*          hfe   = (float*)(ws + o_hfe);
  float*          hbe   = (float*)(ws + o_hbe);
  float*          hbd   = (float*)(ws + o_hbd);
  unsigned short* hbufe = (unsigned short*)(ws + o_hbufe);
  unsigned short* hbufd = (unsigned short*)(ws + o_hbufd);
  unsigned int*   cnte  = (unsigned int*)(ws + o_cnte);
  unsigned int*   cntd  = (unsigned int*)(ws + o_cntd);

  // variant scratch carved from pBe (dead after enc finishes reading it)
  const size_t o_vhb  = o_pBe;                 // 3 x 262,144 variant h exchange
  const size_t o_vcnt = o_pBe + 3*262144ull;   // 3 x 4,096 variant counters

  // zero real counters every call (deterministic graph replays)
  hipMemsetAsync(ws + o_cnte, 0, 8192ull, stream);

  // x -> bf16
  k_f32_to_bf16<<<2048, 256, 0, stream>>>(x, xbf, 64*512*512);

  // pack weights (blocked K split)
  k_pack<<<2048, 256, 0, stream>>>(enc_kf, enc_rf, enc_kb, enc_rb, pBe, 786432, 512, 256);
  k_pack<<<2048, 256, 0, stream>>>(dec_kf, dec_rf, dec_kb, dec_rb, pBd, 1572864, 256, 512);

  // ---- real path (identical to round-5 kernel) ----
  lstm_rec<512, 256, 16, 0><<<32, 256, 0, stream>>>(xbf, pBe, enc_bf, enc_bb, sizes,
                                                    hbufe, cnte, hfe, hbe);
  k_add_bf16<<<2048, 256, 0, stream>>>(hfe, hbe, esum, 64*512*256);

  lstm_rec<256, 512, 32, 0><<<64, 256, 0, stream>>>(esum, pBd, dec_bf, dec_bb, sizes,
                                                    hbufd, cntd, out, hbd);
  k_add_f32<<<2048, 256, 0, stream>>>(out, hbd, 64*512*512);

  // ---- ablation variants: dec-shaped, scratch-only, after d_out finalized ----
  // zero variant counters (pBe region was rewritten by k_pack this call)
  hipMemsetAsync(ws + o_vcnt, 0, 3*4096ull, stream);

  // V1 NOPOLL: publish + h loads kept, wait removed
  lstm_rec<256, 512, 32, 1><<<64, 256, 0, stream>>>(esum, pBd, dec_bf, dec_bb, sizes,
      (unsigned short*)(ws + o_vhb + 0*262144ull), (unsigned int*)(ws + o_vcnt + 0*4096ull),
      hbd, hfe);
  // V2 NOH: poll + publish kept, h loads/MFMAs removed
  lstm_rec<256, 512, 32, 2><<<64, 256, 0, stream>>>(esum, pBd, dec_bf, dec_bb, sizes,
      (unsigned short*)(ws + o_vhb + 1*262144ull), (unsigned int*)(ws + o_vcnt + 1*4096ull),
      hbd, hfe);
  // V3 LOCAL: no poll, no h, no publish — per-WG floor
  lstm_rec<256, 512, 32, 3><<<64, 256, 0, stream>>>(esum, pBd, dec_bf, dec_bb, sizes,
      (unsigned short*)(ws + o_vhb + 2*262144ull), (unsigned int*)(ws + o_vcnt + 2*4096ull),
      hbd, hfe);
}

// Round 9
// 8535.181 us; speedup vs baseline: 1.7443x; 1.7443x over previous
//
#include <hip/hip_runtime.h>
#include <stdint.h>

using short8 = __attribute__((ext_vector_type(8))) short;
using f32x4  = __attribute__((ext_vector_type(4))) float;
typedef unsigned long long ull;

#define DEV static __device__ __forceinline__

DEV unsigned short f2bf(float f){
  unsigned u = __builtin_bit_cast(unsigned, f);
  u = (u + 0x7FFFu + ((u >> 16) & 1u)) >> 16;
  return (unsigned short)u;
}
DEV float sigm(float x){
  float e = __builtin_amdgcn_exp2f(-1.4426950408889634f * x);
  return __builtin_amdgcn_rcpf(1.0f + e);
}
DEV float tanh_(float x){
  float e = __builtin_amdgcn_exp2f(2.885390081777927f * x); // exp(2x)
  return 1.0f - 2.0f * __builtin_amdgcn_rcpf(e + 1.0f);
}

// ---------------- aux kernels ----------------

__global__ void k_f32_to_bf16(const float* __restrict__ in, unsigned short* __restrict__ out, int n){
  int stride = gridDim.x * blockDim.x * 4;
  for (int i = (blockIdx.x * blockDim.x + threadIdx.x) * 4; i < n; i += stride){
    float4 v = *(const float4*)(in + i);
    ushort4 o4;
    o4.x = f2bf(v.x); o4.y = f2bf(v.y); o4.z = f2bf(v.z); o4.w = f2bf(v.w);
    *(ushort4*)(out + i) = o4;
  }
}

__global__ void k_add_bf16(const float* __restrict__ a, const float* __restrict__ b,
                           unsigned short* __restrict__ out, int n){
  int stride = gridDim.x * blockDim.x * 4;
  for (int i = (blockIdx.x * blockDim.x + threadIdx.x) * 4; i < n; i += stride){
    float4 va = *(const float4*)(a + i);
    float4 vb = *(const float4*)(b + i);
    ushort4 o4;
    o4.x = f2bf(va.x + vb.x); o4.y = f2bf(va.y + vb.y);
    o4.z = f2bf(va.z + vb.z); o4.w = f2bf(va.w + vb.w);
    *(ushort4*)(out + i) = o4;
  }
}

__global__ void k_add_f32(float* __restrict__ o, const float* __restrict__ b, int n){
  int stride = gridDim.x * blockDim.x * 4;
  for (int i = (blockIdx.x * blockDim.x + threadIdx.x) * 4; i < n; i += stride){
    float4 vo = *(const float4*)(o + i);
    float4 vb = *(const float4*)(b + i);
    vo.x += vb.x; vo.y += vb.y; vo.z += vb.z; vo.w += vb.w;
    *(float4*)(o + i) = vo;
  }
}

// Pack [k; r] (f32, [K,4U] each, K split KX|U) into per-(dir,wg,wave,ktile,ntile)
// MFMA B-fragment order (BLOCKED K split: wave w owns ktiles 6w..6w+5)
__global__ void k_pack(const float* __restrict__ k0, const float* __restrict__ r0,
                       const float* __restrict__ k1, const float* __restrict__ r1,
                       unsigned short* __restrict__ out, int E, int KX, int U){
  int n = 2 * E;
  int stride = gridDim.x * blockDim.x;
  for (int i = blockIdx.x * blockDim.x + threadIdx.x; i < n; i += stride){
    int d = i / E, r = i % E;
    const float* Km = d ? k1 : k0;
    const float* Rm = d ? r1 : r0;
    int j    = r & 7;  int q = r >> 3;
    int lane = q & 63; q >>= 6;
    int nt   = q & 3;  q >>= 2;
    int kt   = q % 6;  q /= 6;
    int w    = q & 3;  int wg = q >> 2;
    int k    = (w*6 + kt)*32 + ((lane >> 4) << 3) + j;
    int col  = nt * U + wg*16 + (lane & 15);   // gate-major global column
    float v  = (k < KX) ? Km[(size_t)k * (4*U) + col]
                        : Rm[(size_t)(k - KX) * (4*U) + col];
    out[i] = f2bf(v);
  }
}

// ---------------- persistent recurrence kernel ----------------
// R5 skeleton with decontended sync:
//  - per-WG flag lines (plain relaxed agent stores, NO atomic RMW)
//  - each h-wave polls only its producer subset (<=12 lines), s_sleep(2) backoff
//  - producer: gate -> h sc1 stores -> __syncthreads (drains all waves' vmcnt,
//    h LLC-visible) -> tid0 flag store -> out stores / x prefetch (overlapped)
// Skew/overwrite safety: the 3 h-waves' producer ranges partition all WGs, and
// the scatter barrier joins them -> WG-collective wait on all flags >= s, same
// invariant as R5's counter (max skew 1 step < dbuf period 2).
template<int KX, int U, int WGS>
__global__ __launch_bounds__(256, 1)
void lstm_rec(const unsigned short* __restrict__ xab,    // [64][512][KX] bf16
              const unsigned short* __restrict__ packedB,
              const float* __restrict__ bias_f,
              const float* __restrict__ bias_b,
              const int*   __restrict__ sizes,
              unsigned short* __restrict__ hbuf,         // [2 dirs][2][64][U] bf16
              unsigned int*  __restrict__ flags,         // [2 dirs][WGS*32]
              float* __restrict__ out_f,                 // [64][512][U]
              float* __restrict__ out_b)
{
  constexpr int KTW = 6;               // ktiles per wave (blocked)
  constexpr int T   = 512;

  const int tid  = threadIdx.x;
  const int w    = tid >> 6;
  const int lane = tid & 63;
  const int dir  = (blockIdx.x >= WGS) ? 1 : 0;
  const int wg   = dir ? (int)blockIdx.x - WGS : (int)blockIdx.x;

  const unsigned short* pB = packedB + (size_t)dir * ((size_t)WGS*4*KTW*4*512)
                                     + (size_t)((wg*4 + w)*KTW)*4*512;
  unsigned short* hb  = hbuf + (size_t)dir * (2*64*U);
  unsigned int*   flg = flags + dir * (WGS*32);
  const float* bias = dir ? bias_b : bias_f;
  float* outp       = dir ? out_b : out_f;

  // producer subset this wave must wait for: units [ulo, uhi) -> WGs [p_lo, p_hi)
  const int ulo = (192*w - KX) > 0 ? (192*w - KX) : 0;
  int uhi_ = 192*(w + 1) - KX; if (uhi_ > U) uhi_ = U; if (uhi_ < 0) uhi_ = 0;
  const int uhi = uhi_;
  const bool has_h = uhi > ulo;
  const int p_lo = ulo >> 4;               // 16 units per producer WG
  const int np   = has_h ? ((uhi + 15) >> 4) - p_lo : 0;

  // preload B fragments (step-invariant): 96 VGPRs
  short8 bfr[KTW][4];
  #pragma unroll
  for (int kt = 0; kt < KTW; ++kt)
    #pragma unroll
    for (int nt = 0; nt < 4; ++nt)
      bfr[kt][nt] = *(const short8*)(pB + ((kt*4 + nt)*512) + lane*8);

  // gate-phase ownership: unit u_l (0..15), rows rb..rb+3
  const int u_l = tid & 15;
  const int rb  = (tid >> 4) * 4;
  const int ug  = wg*16 + u_l;
  float bz[4]; int sz[4];
  #pragma unroll
  for (int g = 0; g < 4; ++g) bz[g] = bias[g*U + ug];
  #pragma unroll
  for (int r = 0; r < 4; ++r) sz[r] = sizes[rb + r];
  float c[4]    = {0.f,0.f,0.f,0.f};
  float hreg[4] = {0.f,0.f,0.f,0.f};

  __shared__ float part[4][64][68];

  const int arow  = lane & 15;
  const int kgrp  = (lane >> 4) * 8;
  const int rquad = (lane >> 4) * 4;

  // x fragments, prefetched one step ahead
  short8 xreg[KTW][4];
  {
    const int t0 = dir ? T - 1 : 0;
    #pragma unroll
    for (int kt = 0; kt < KTW; ++kt){
      const int kg = (w*KTW + kt) * 32;
      if (kg < KX){
        #pragma unroll
        for (int mt = 0; mt < 4; ++mt)
          xreg[kt][mt] = *(const short8*)(xab + ((size_t)((mt*16 + arow)*T + t0))*KX + (kg + kgrp));
      }
    }
  }

  for (int s = 0; s < T; ++s){
    const int t   = dir ? (T - 1 - s) : s;
    const int par = s & 1;

    f32x4 acc[4][4];
    #pragma unroll
    for (int mt = 0; mt < 4; ++mt)
      #pragma unroll
      for (int nt = 0; nt < 4; ++nt)
        acc[mt][nt] = (f32x4){0.f, 0.f, 0.f, 0.f};

    // ---- x MFMAs ----
    #pragma unroll
    for (int kt = 0; kt < KTW; ++kt){
      const int kg = (w*KTW + kt) * 32;
      if (kg < KX){
        #pragma unroll
        for (int mt = 0; mt < 4; ++mt)
          #pragma unroll
          for (int nt = 0; nt < 4; ++nt)
            acc[mt][nt] = __builtin_amdgcn_mfma_f32_16x16x32_bf16(xreg[kt][mt], bfr[kt][nt], acc[mt][nt], 0, 0, 0);
      }
    }

    if (s > 0 && has_h){
      // ---- poll own producer subset (<=12 flag lines), with backoff ----
      const unsigned tgt = (unsigned)s;
      for (;;){
        unsigned v = (lane < np)
          ? __hip_atomic_load(&flg[(p_lo + lane)*32], __ATOMIC_RELAXED, __HIP_MEMORY_SCOPE_AGENT)
          : tgt;
        if (__all(v >= tgt)) break;
        __builtin_amdgcn_s_sleep(2);
      }
      __builtin_amdgcn_sched_barrier(0);
      // ---- h loads + h MFMAs ----
      #pragma unroll
      for (int kt = 0; kt < KTW; ++kt){
        const int kg = (w*KTW + kt) * 32;
        if (kg >= KX){
          #pragma unroll
          for (int mt = 0; mt < 4; ++mt){
            const ull* hp = (const ull*)
                (hb + (size_t)par*64*U + (size_t)(mt*16 + arow)*U + (kg - KX + kgrp));
            ulonglong2 u;
            u.x = __hip_atomic_load(hp,     __ATOMIC_RELAXED, __HIP_MEMORY_SCOPE_AGENT);
            u.y = __hip_atomic_load(hp + 1, __ATOMIC_RELAXED, __HIP_MEMORY_SCOPE_AGENT);
            short8 a = __builtin_bit_cast(short8, u);
            #pragma unroll
            for (int nt = 0; nt < 4; ++nt)
              acc[mt][nt] = __builtin_amdgcn_mfma_f32_16x16x32_bf16(a, bfr[kt][nt], acc[mt][nt], 0, 0, 0);
          }
        }
      }
    }

    // ---- D-frag scatter: b128 ----
    #pragma unroll
    for (int mt = 0; mt < 4; ++mt)
      #pragma unroll
      for (int nt = 0; nt < 4; ++nt)
        *(f32x4*)&part[w][nt*16 + arow][mt*16 + rquad] = acc[mt][nt];

    __syncthreads();

    // ---- gate phase ----
    f32x4 zg[4];
    #pragma unroll
    for (int g = 0; g < 4; ++g){
      const int cb = g*16 + u_l;
      f32x4 v = *(const f32x4*)&part[0][cb][rb];
      #pragma unroll
      for (int ww = 1; ww < 4; ++ww)
        v += *(const f32x4*)&part[ww][cb][rb];
      zg[g] = v;
    }

    #pragma unroll
    for (int r = 0; r < 4; ++r){
      float ig = sigm (zg[0][r] + bz[0]);
      float fg = sigm (zg[1][r] + bz[1]);
      float gg = tanh_(zg[2][r] + bz[2]);
      float og = sigm (zg[3][r] + bz[3]);
      float cn = fg * c[r] + ig * gg;
      float hn = og * tanh_(cn);
      bool m  = (t < sz[r]);
      c[r] = m ? cn : c[r];
      float h = m ? hn : hreg[r];
      hreg[r] = h;
      if (s != T - 1)
        __hip_atomic_store(&hb[(size_t)(par ^ 1)*64*U + (size_t)(rb + r)*U + ug],
                           (unsigned short)f2bf(h),
                           __ATOMIC_RELAXED, __HIP_MEMORY_SCOPE_AGENT);
    }

    __syncthreads();   // drains every wave's vmcnt: h stores visible at LLC

    if (s != T - 1){
      // publish: plain flag store on this WG's own line (no RMW)
      if (tid == 0)
        __hip_atomic_store(&flg[wg*32], (unsigned)(s + 1),
                           __ATOMIC_RELAXED, __HIP_MEMORY_SCOPE_AGENT);
    }

    // out store AFTER the publish (acks overlap next step's wait)
    #pragma unroll
    for (int r = 0; r < 4; ++r)
      outp[((size_t)(rb + r)*T + t)*U + ug] = hreg[r];

    // x prefetch for next step (HBM latency absorbed into the wait)
    if (s != T - 1){
      const int tn = dir ? t - 1 : t + 1;
      #pragma unroll
      for (int kt = 0; kt < KTW; ++kt){
        const int kg = (w*KTW + kt) * 32;
        if (kg < KX){
          #pragma unroll
          for (int mt = 0; mt < 4; ++mt)
            xreg[kt][mt] = *(const short8*)(xab + ((size_t)((mt*16 + arow)*T + tn))*KX + (kg + kgrp));
        }
      }
    }
  }
}

// ---------------- launch ----------------

extern "C" void kernel_launch(void* const* d_in, const int* in_sizes, int n_in,
                              void* d_out, int out_size, void* d_ws, size_t ws_size,
                              hipStream_t stream){
  const float* x      = (const float*)d_in[0];
  const int*   sizes  = (const int*)  d_in[1];
  const float* enc_kf = (const float*)d_in[2];
  const float* enc_rf = (const float*)d_in[3];
  const float* enc_bf = (const float*)d_in[4];
  const float* enc_kb = (const float*)d_in[5];
  const float* enc_rb = (const float*)d_in[6];
  const float* enc_bb = (const float*)d_in[7];
  const float* dec_kf = (const float*)d_in[8];
  const float* dec_rf = (const float*)d_in[9];
  const float* dec_bf = (const float*)d_in[10];
  const float* dec_kb = (const float*)d_in[11];
  const float* dec_rb = (const float*)d_in[12];
  const float* dec_bb = (const float*)d_in[13];
  float* out = (float*)d_out;
  char*  ws  = (char*)d_ws;

  const size_t o_xbf   = 0;                        // 33,554,432  x bf16
  const size_t o_esum  = o_xbf   + 33554432ull;    // 16,777,216  enc sum bf16
  const size_t o_pBe   = o_esum  + 16777216ull;    //  3,145,728  packed enc
  const size_t o_pBd   = o_pBe   + 3145728ull;     //  6,291,456  packed dec
  const size_t o_hfe   = o_pBd   + 6291456ull;     // 33,554,432  enc fwd h f32
  const size_t o_hbe   = o_hfe   + 33554432ull;    // 33,554,432  enc bwd h f32
  const size_t o_hbd   = o_hbe   + 33554432ull;    // 67,108,864  dec bwd h f32
  const size_t o_hbufe = o_hbd   + 67108864ull;    //    131,072  enc h exchange
  const size_t o_hbufd = o_hbufe + 131072ull;      //    262,144  dec h exchange
  const size_t o_flge  = o_hbufd + 262144ull;      //      8,192  enc flags (2 dirs x 16 x 128B)
  const size_t o_flgd  = o_flge  + 8192ull;        //      8,192  dec flags (2 dirs x 32 x 128B)
  const size_t total   = o_flgd  + 8192ull;
  if (ws_size < total) return;

  unsigned short* xbf   = (unsigned short*)(ws + o_xbf);
  unsigned short* esum  = (unsigned short*)(ws + o_esum);
  unsigned short* pBe   = (unsigned short*)(ws + o_pBe);
  unsigned short* pBd   = (unsigned short*)(ws + o_pBd);
  float*          hfe   = (float*)(ws + o_hfe);
  float*          hbe   = (float*)(ws + o_hbe);
  float*          hbd   = (float*)(ws + o_hbd);
  unsigned short* hbufe = (unsigned short*)(ws + o_hbufe);
  unsigned short* hbufd = (unsigned short*)(ws + o_hbufd);
  unsigned int*   flge  = (unsigned int*)(ws + o_flge);
  unsigned int*   flgd  = (unsigned int*)(ws + o_flgd);

  // zero flags every call (deterministic graph replays)
  hipMemsetAsync(ws + o_flge, 0, 16384ull, stream);

  // x -> bf16
  k_f32_to_bf16<<<2048, 256, 0, stream>>>(x, xbf, 64*512*512);

  // pack weights (blocked K split)
  k_pack<<<2048, 256, 0, stream>>>(enc_kf, enc_rf, enc_kb, enc_rb, pBe, 786432, 512, 256);
  k_pack<<<2048, 256, 0, stream>>>(dec_kf, dec_rf, dec_kb, dec_rb, pBd, 1572864, 256, 512);

  // encoder bilstm (fwd 16 WGs + bwd 16 WGs)
  lstm_rec<512, 256, 16><<<32, 256, 0, stream>>>(xbf, pBe, enc_bf, enc_bb, sizes,
                                                 hbufe, flge, hfe, hbe);
  // enc_sum = bf16(hf + hb)
  k_add_bf16<<<2048, 256, 0, stream>>>(hfe, hbe, esum, 64*512*256);

  // decoder bilstm: fwd writes d_out directly, bwd to ws
  lstm_rec<256, 512, 32><<<64, 256, 0, stream>>>(esum, pBd, dec_bf, dec_bb, sizes,
                                                 hbufd, flgd, out, hbd);
  // d_out += dec bwd
  k_add_f32<<<2048, 256, 0, stream>>>(out, hbd, 64*512*512);
}